// Round 13
// baseline (659.387 us; speedup 1.0000x reference)
//
#include <hip/hip_runtime.h>
#include <stdint.h>

#define NN 100000
#define NE 1600000
#define NB 4096
#define FIN 92
#define H 51
#define H3 153
#define TSTEPS 7
#define SCAN_B 391   // ceil(NN/256)
#define GG_BLOCKS 1024
#define GG_CHUNKS (NN / 32)   // 3125

// ---------------- static device workspace (BSS; no hipMalloc) ----------------
__device__ __align__(16) float g_x1[(size_t)NN * 52 + 64];   // lrelu(x@W1+b1), stride 52 (pad=0)
__device__ __align__(16) float g_p[(size_t)NN * 52 + 64];    // x1 @ We1x (node part of edge transform)
__device__ float g_xr[NN];                     // x1 @ att_r
__device__ float g_agg[(size_t)NN * H + 64];   // softmax-weighted sum of lrelu(xe) per dst
__device__ float g_x2[(size_t)NN * H + 64];    // node state after GRU1 + relu
__device__ float g_xl[(size_t)NN * H + 64];    // x2 @ Wm
__device__ float g_al[NN];                     // xl @ att_src
__device__ int   g_gs[NB + 2];                 // graph start offsets (batch is sorted)
__device__ float g_wg1[H * H * 8];             // GRU1 weights interleaved [k][j][8]
__device__ float g_bg1[64 * 8];
__device__ float g_wg2[H * H * 8];
__device__ float g_bg2[64 * 8];
__device__ float g_wv[64];                     // Wm @ att_dst
// CSR scratch
__device__ int   g_cnt[NN];
__device__ int   g_rp[NN + 1];
__device__ int   g_cur[NN];
__device__ int   g_src[NE + 4];                // src node id, grouped by dst
__device__ __align__(16) float g_eac[(size_t)NE * 12 + 16];  // edge_attr in CSR order, 12-float rows
__device__ int   g_bsum[512];
__device__ int   g_boff[512];

__device__ __forceinline__ float lrelu(float v) { return v > 0.f ? v : 0.01f * v; }
__device__ __forceinline__ float elu1(float v) { return v > 0.f ? v : expm1f(v); }
__device__ __forceinline__ float sigm(float v) { return 1.f / (1.f + __expf(-v)); }

__device__ __forceinline__ float bflo(uint32_t w) { union { uint32_t u; float f; } c; c.u = w << 16; return c.f; }
__device__ __forceinline__ float bfhi(uint32_t w) { union { uint32_t u; float f; } c; c.u = w & 0xffff0000u; return c.f; }
// RNE float->bf16 (returned in low 16 bits)
__device__ __forceinline__ uint32_t f2bf(float f) {
    uint32_t u = __float_as_uint(f);
    return (u + 0x7FFFu + ((u >> 16) & 1u)) >> 16;
}

__device__ __forceinline__ float wave_sum(float v) {
    v += __shfl_xor(v, 32, 64);
    v += __shfl_xor(v, 16, 64);
    v += __shfl_xor(v, 8, 64);
    v += __shfl_xor(v, 4, 64);
    v += __shfl_xor(v, 2, 64);
    v += __shfl_xor(v, 1, 64);
    return v;
}
__device__ __forceinline__ void wave_sum4(float& a, float& b, float& c, float& d) {
    a += __shfl_xor(a, 32, 64); b += __shfl_xor(b, 32, 64); c += __shfl_xor(c, 32, 64); d += __shfl_xor(d, 32, 64);
    a += __shfl_xor(a, 16, 64); b += __shfl_xor(b, 16, 64); c += __shfl_xor(c, 16, 64); d += __shfl_xor(d, 16, 64);
    a += __shfl_xor(a, 8, 64);  b += __shfl_xor(b, 8, 64);  c += __shfl_xor(c, 8, 64);  d += __shfl_xor(d, 8, 64);
    a += __shfl_xor(a, 4, 64);  b += __shfl_xor(b, 4, 64);  c += __shfl_xor(c, 4, 64);  d += __shfl_xor(d, 4, 64);
    a += __shfl_xor(a, 2, 64);  b += __shfl_xor(b, 2, 64);  c += __shfl_xor(c, 2, 64);  d += __shfl_xor(d, 2, 64);
    a += __shfl_xor(a, 1, 64);  b += __shfl_xor(b, 1, 64);  c += __shfl_xor(c, 1, 64);  d += __shfl_xor(d, 1, 64);
}

// dot4 helper — plain inline function, immune to macro member-name capture
__device__ __forceinline__ float d4(float acc, float4 t, float4 wv) {
    return fmaf(t.x, wv.x, fmaf(t.y, wv.y, fmaf(t.z, wv.z, fmaf(t.w, wv.w, acc))));
}

// ---------------- prep ----------------
// zero histogram + graph-start offsets, one launch
__global__ __launch_bounds__(256) void k_init(const int* __restrict__ batch) {
    int n = blockIdx.x * 256 + threadIdx.x;
    if (n >= NN) return;
    g_cnt[n] = 0;
    int bn = batch[n];
    int bp = (n == 0) ? -1 : batch[n - 1];
    for (int b = bp + 1; b <= bn; ++b) g_gs[b] = n;
    if (n == NN - 1) for (int b = bn + 1; b <= NB; ++b) g_gs[b] = NN;
}

// pack both GRUs + wv in one launch
__global__ void k_prep(const float* __restrict__ Wih1, const float* __restrict__ bih1,
                       const float* __restrict__ Whh1, const float* __restrict__ bhh1,
                       const float* __restrict__ Wih2, const float* __restrict__ bih2,
                       const float* __restrict__ Whh2, const float* __restrict__ bhh2,
                       const float* __restrict__ Wm, const float* __restrict__ ad) {
    int id = blockIdx.x * 256 + threadIdx.x;
    int which = 0;
    const float *Wih, *bih, *Whh, *bhh;
    if (id < H * H) {
        which = 0; Wih = Wih1; bih = bih1; Whh = Whh1; bhh = bhh1;
    } else if (id < 2 * H * H) {
        which = 1; id -= H * H; Wih = Wih2; bih = bih2; Whh = Whh2; bhh = bhh2;
    } else {
        int k = id - 2 * H * H;
        if (k < 64) {
            float a = 0.f;
            if (k < H) for (int j = 0; j < H; ++j) a = fmaf(Wm[k * H + j], ad[j], a);
            g_wv[k] = a;
        }
        return;
    }
    float* Wg = which ? g_wg2 : g_wg1;
    float* bg = which ? g_bg2 : g_bg1;
    int k = id / H, j = id - k * H;
    float* o = Wg + (size_t)id * 8;
    o[0] = Wih[k * H3 + j];
    o[1] = Wih[k * H3 + H + j];
    o[2] = Wih[k * H3 + 2 * H + j];
    o[3] = Whh[k * H3 + j];
    o[4] = Whh[k * H3 + H + j];
    o[5] = Whh[k * H3 + 2 * H + j];
    o[6] = 0.f; o[7] = 0.f;
    if (id < H) {
        float* ob = bg + (size_t)id * 8;
        ob[0] = bih[id]; ob[1] = bih[H + id]; ob[2] = bih[2 * H + id];
        ob[3] = bhh[id]; ob[4] = bhh[H + id]; ob[5] = bhh[2 * H + id];
        ob[6] = 0.f; ob[7] = 0.f;
    }
}

// ---------------- CSR build ----------------
__global__ __launch_bounds__(256) void k_count(const int* __restrict__ ei) {
    int e = blockIdx.x * 256 + threadIdx.x;
    if (e >= NE) return;
    atomicAdd(&g_cnt[ei[NE + e]], 1);
}

__global__ __launch_bounds__(256) void k_scan1() {
    __shared__ int sm[256];
    int tid = threadIdx.x;
    int i = blockIdx.x * 256 + tid;
    sm[tid] = (i < NN) ? g_cnt[i] : 0;
    __syncthreads();
#pragma unroll
    for (int off = 1; off < 256; off <<= 1) {
        int t = (tid >= off) ? sm[tid - off] : 0;
        __syncthreads();
        sm[tid] += t;
        __syncthreads();
    }
    if (i < NN) g_rp[i + 1] = sm[tid];
    if (tid == 255) g_bsum[blockIdx.x] = sm[255];
}

__global__ void k_scan2() {
    __shared__ int sm[512];
    int tid = threadIdx.x;
    sm[tid] = (tid < SCAN_B) ? g_bsum[tid] : 0;
    __syncthreads();
#pragma unroll
    for (int off = 1; off < 512; off <<= 1) {
        int t = (tid >= off) ? sm[tid - off] : 0;
        __syncthreads();
        sm[tid] += t;
        __syncthreads();
    }
    if (tid < SCAN_B) g_boff[tid] = (tid == 0) ? 0 : sm[tid - 1];
}

__global__ __launch_bounds__(256) void k_scan3() {
    int i = blockIdx.x * 256 + threadIdx.x;
    if (i >= NN) return;
    int v = g_rp[i + 1] + g_boff[blockIdx.x];
    g_rp[i + 1] = v;
    if (i == 0) { g_rp[0] = 0; g_cur[0] = 0; }
    if (i + 1 < NN) g_cur[i + 1] = v;
}

__global__ __launch_bounds__(256) void k_fill(const int* __restrict__ ei, const float* __restrict__ ea) {
    int e = blockIdx.x * 256 + threadIdx.x;
    if (e >= NE) return;
    int d = ei[NE + e];
    int pos = atomicAdd(&g_cur[d], 1);
    g_src[pos] = ei[e];
    const float2* s2 = (const float2*)(ea + (size_t)e * 10);
    float2 v0 = s2[0], v1 = s2[1], v2 = s2[2], v3 = s2[3], v4 = s2[4];
    float2* d2 = (float2*)(g_eac + (size_t)pos * 12);
    d2[0] = v0; d2[1] = v1; d2[2] = v2; d2[3] = v3; d2[4] = v4;
    d2[5] = make_float2(0.f, 0.f);
}

// ---------------- lin1 (+P fused): x1 = lrelu(x@W1+b1), xr = x1@att_r, P = x1@We1x ----------------
__global__ __launch_bounds__(256, 3) void k_lin1(const float* __restrict__ x, const float* __restrict__ W1,
                                                 const float* __restrict__ b1, const float* __restrict__ attr_,
                                                 const float* __restrict__ We1) {
    int n = blockIdx.x * 256 + threadIdx.x;
    if (n >= NN) return;
    const float4* xq4 = (const float4*)(x + (size_t)n * FIN);
    float acc[H];
#pragma unroll
    for (int h = 0; h < H; ++h) acc[h] = 0.f;
#pragma unroll 1
    for (int q = 0; q < FIN / 4; ++q) {
        float4 v = xq4[q];
        const float* wr = W1 + (4 * q) * H;
#pragma unroll
        for (int h = 0; h < H; ++h)
            acc[h] = fmaf(v.x, wr[h], fmaf(v.y, wr[H + h], fmaf(v.z, wr[2 * H + h], fmaf(v.w, wr[3 * H + h], acc[h]))));
    }
    float xrv = 0.f;
    float* xo = g_x1 + (size_t)n * 52;
#pragma unroll
    for (int h = 0; h < H; ++h) {
        float v = lrelu(acc[h] + b1[h]);
        acc[h] = v;            // keep activated row in registers for the P pass
        xo[h] = v;
        xrv = fmaf(v, attr_[h], xrv);
    }
    xo[H] = 0.f;
    g_xr[n] = xrv;
    // P row: p[h] = sum_k acc[k] * We1[k*H+h]  (h-outer so acc[] indices stay compile-time)
    float* po = g_p + (size_t)n * 52;
#pragma unroll 1
    for (int h = 0; h < H; ++h) {
        float ph = 0.f;
#pragma unroll
        for (int k = 0; k < H; ++k) ph = fmaf(acc[k], We1[k * H + h], ph);
        po[h] = ph;
    }
    po[H] = 0.f;
}

// ---------------- GATEConv: wave per dst node, lane = channel; 1-deep P-row prefetch ----------------
#define MKE(q) make_float4( \
    (4*(q)+0) < 10 ? We1[(51 + 4*(q)+0) * H + lj] : 0.f, \
    (4*(q)+1) < 10 ? We1[(51 + 4*(q)+1) * H + lj] : 0.f, \
    (4*(q)+2) < 10 ? We1[(51 + 4*(q)+2) * H + lj] : 0.f, \
    (4*(q)+3) < 10 ? We1[(51 + 4*(q)+3) * H + lj] : 0.f)

__global__ __launch_bounds__(256, 4) void k_gate(const float* __restrict__ We1, const float* __restrict__ attl) {
    int lane = threadIdx.x & 63;
    int lj = lane < H ? lane : H - 1;
    int n = __builtin_amdgcn_readfirstlane(blockIdx.x * 4 + (threadIdx.x >> 6));
    float4 eq0 = MKE(0), eq1 = MKE(1), eq2 = MKE(2);
    float attlv = attl[lj];
    float xrd = g_xr[n];
    int rs = g_rp[n], re = g_rp[n + 1];
    float accH = 0.f, den = 0.f;
    int nb = (re - rs) >> 2;
    int idx = rs;
    float pv0 = 0.f, pv1 = 0.f, pv2 = 0.f, pv3 = 0.f;
    if (nb > 0) {
        int s0 = __builtin_amdgcn_readfirstlane(g_src[idx]);
        int s1 = __builtin_amdgcn_readfirstlane(g_src[idx + 1]);
        int s2 = __builtin_amdgcn_readfirstlane(g_src[idx + 2]);
        int s3 = __builtin_amdgcn_readfirstlane(g_src[idx + 3]);
        pv0 = g_p[(size_t)s0 * 52 + lane];
        pv1 = g_p[(size_t)s1 * 52 + lane];
        pv2 = g_p[(size_t)s2 * 52 + lane];
        pv3 = g_p[(size_t)s3 * 52 + lane];
    }
#pragma unroll 1
    for (int blk = 0; blk < nb; ++blk) {
        int ci = idx;
        float cp0 = pv0, cp1 = pv1, cp2 = pv2, cp3 = pv3;
        idx += 4;
        if (blk + 1 < nb) {   // prefetch next block's P rows while computing this one
            int s0 = __builtin_amdgcn_readfirstlane(g_src[idx]);
            int s1 = __builtin_amdgcn_readfirstlane(g_src[idx + 1]);
            int s2 = __builtin_amdgcn_readfirstlane(g_src[idx + 2]);
            int s3 = __builtin_amdgcn_readfirstlane(g_src[idx + 3]);
            pv0 = g_p[(size_t)s0 * 52 + lane];
            pv1 = g_p[(size_t)s1 * 52 + lane];
            pv2 = g_p[(size_t)s2 * 52 + lane];
            pv3 = g_p[(size_t)s3 * 52 + lane];
        }
        const float4* ep0 = (const float4*)(g_eac + (size_t)ci * 12);
        const float4* ep1 = (const float4*)(g_eac + (size_t)(ci + 1) * 12);
        const float4* ep2 = (const float4*)(g_eac + (size_t)(ci + 2) * 12);
        const float4* ep3 = (const float4*)(g_eac + (size_t)(ci + 3) * 12);
        float xe0 = cp0, xe1 = cp1, xe2 = cp2, xe3 = cp3;
        xe0 = d4(xe0, ep0[0], eq0); xe0 = d4(xe0, ep0[1], eq1); xe0 = d4(xe0, ep0[2], eq2);
        xe1 = d4(xe1, ep1[0], eq0); xe1 = d4(xe1, ep1[1], eq1); xe1 = d4(xe1, ep1[2], eq2);
        xe2 = d4(xe2, ep2[0], eq0); xe2 = d4(xe2, ep2[1], eq1); xe2 = d4(xe2, ep2[2], eq2);
        xe3 = d4(xe3, ep3[0], eq0); xe3 = d4(xe3, ep3[1], eq1); xe3 = d4(xe3, ep3[2], eq2);
        float l0 = lrelu(xe0), l1 = lrelu(xe1), l2 = lrelu(xe2), l3 = lrelu(xe3);
        float p0 = (lane < H) ? l0 * attlv : 0.f;
        float p1 = (lane < H) ? l1 * attlv : 0.f;
        float p2 = (lane < H) ? l2 * attlv : 0.f;
        float p3 = (lane < H) ? l3 * attlv : 0.f;
        wave_sum4(p0, p1, p2, p3);
        float e0 = __expf(lrelu(p0 + xrd));
        float e1 = __expf(lrelu(p1 + xrd));
        float e2 = __expf(lrelu(p2 + xrd));
        float e3 = __expf(lrelu(p3 + xrd));
        accH = fmaf(e0, l0, accH); den += e0;
        accH = fmaf(e1, l1, accH); den += e1;
        accH = fmaf(e2, l2, accH); den += e2;
        accH = fmaf(e3, l3, accH); den += e3;
    }
    for (; idx < re; ++idx) {
        int s0 = __builtin_amdgcn_readfirstlane(g_src[idx]);
        float pvs = g_p[(size_t)s0 * 52 + lane];
        const float4* ep0 = (const float4*)(g_eac + (size_t)idx * 12);
        float xe0 = pvs;
        xe0 = d4(xe0, ep0[0], eq0); xe0 = d4(xe0, ep0[1], eq1); xe0 = d4(xe0, ep0[2], eq2);
        float l0 = lrelu(xe0);
        float a0 = wave_sum((lane < H) ? l0 * attlv : 0.f);
        float e0 = __expf(lrelu(a0 + xrd));
        accH = fmaf(e0, l0, accH); den += e0;
    }
    if (lane < H) g_agg[(size_t)n * H + lane] = accH / (den + 1e-16f);
}

// ---------------- gate(We2) + GRU1 + xl/al fused: persistent blocks, LDS bf16 GRU1 weights ----------------
// Each block stages g_wg1 (bf16-packed, 31.2 KB) once, then loops over 32-node chunks.
__global__ __launch_bounds__(256) void k_gategru(const float* __restrict__ We2, const float* __restrict__ gb,
                                                 const float* __restrict__ Wm, const float* __restrict__ asrc) {
    __shared__ uint32_t wA[H * H];
    __shared__ uint32_t wB[H * H];
    __shared__ uint32_t wC[H * H];
    __shared__ float lbc[4][52][8];
    int tid = threadIdx.x;
    for (int i = tid; i < H * H; i += 256) {
        const float* s = g_wg1 + (size_t)i * 8;
        wA[i] = f2bf(s[0]) | (f2bf(s[1]) << 16);
        wB[i] = f2bf(s[2]) | (f2bf(s[3]) << 16);
        wC[i] = f2bf(s[4]) | (f2bf(s[5]) << 16);
    }
    __syncthreads();
    int w = tid >> 6;
    int lane = tid & 63;
    int lj = lane < H ? lane : H - 1;
    const float4* bp = (const float4*)(g_bg1 + lane * 8);
    float4 b0 = bp[0];
    float4 b1v = bp[1];
    float gbl = gb[lj];
    float asl = asrc[lj];
#pragma unroll 1
    for (int chunk = blockIdx.x; chunk < GG_CHUNKS; chunk += GG_BLOCKS) {
        int base = __builtin_amdgcn_readfirstlane(chunk * 32 + w * 8);
        float xj[8];
#pragma unroll
        for (int m = 0; m < 8; ++m) xj[m] = g_x1[(size_t)(base + m) * 52 + lane];
        // phase 1: hb = elu(agg @ We2 + gb); agg broadcast via uniform s_load
        float ac[8];
#pragma unroll
        for (int m = 0; m < 8; ++m) ac[m] = 0.f;
#pragma unroll 1
        for (int k = 0; k < H; ++k) {
            float wv = We2[k * H + lj];
#pragma unroll
            for (int m = 0; m < 8; ++m)
                ac[m] = fmaf(g_agg[(size_t)(base + m) * H + k], wv, ac[m]);
        }
        float hb[8];
#pragma unroll
        for (int m = 0; m < 8; ++m) hb[m] = elu1(ac[m] + gbl);
        if (lane < H) {
#pragma unroll
            for (int m = 0; m < 8; ++m) lbc[w][lane][m] = hb[m];
        }
        // phase 2: GRU1 — weights from LDS bf16, hb via LDS broadcast, x via s_load
        float gir[8], giz[8], gin[8], ghr[8], ghz[8], ghn[8];
#pragma unroll
        for (int m = 0; m < 8; ++m) { gir[m] = 0; giz[m] = 0; gin[m] = 0; ghr[m] = 0; ghz[m] = 0; ghn[m] = 0; }
#pragma unroll 1
        for (int k = 0; k < H; ++k) {
            uint32_t wa = wA[k * H + lj];
            uint32_t wb = wB[k * H + lj];
            uint32_t wc = wC[k * H + lj];
            float w0x = bflo(wa), w0y = bfhi(wa), w0z = bflo(wb);
            float w0w = bfhi(wb), w1x = bflo(wc), w1y = bfhi(wc);
            float4 h0 = *(const float4*)&lbc[w][k][0];
            float4 h1 = *(const float4*)&lbc[w][k][4];
            float hk[8] = { h0.x, h0.y, h0.z, h0.w, h1.x, h1.y, h1.z, h1.w };
#pragma unroll
            for (int m = 0; m < 8; ++m) {
                float xk = g_x1[(size_t)(base + m) * 52 + k];   // uniform -> s_load
                gir[m] = fmaf(hk[m], w0x, gir[m]); giz[m] = fmaf(hk[m], w0y, giz[m]); gin[m] = fmaf(hk[m], w0z, gin[m]);
                ghr[m] = fmaf(xk, w0w, ghr[m]);    ghz[m] = fmaf(xk, w1x, ghz[m]);    ghn[m] = fmaf(xk, w1y, ghn[m]);
            }
        }
        float o2[8];
#pragma unroll
        for (int m = 0; m < 8; ++m) {
            float r = sigm(gir[m] + b0.x + ghr[m] + b0.w);
            float z = sigm(giz[m] + b0.y + ghz[m] + b1v.x);
            float nn2 = tanhf(gin[m] + b0.z + r * (ghn[m] + b1v.y));
            o2[m] = fmaxf((1.f - z) * nn2 + z * xj[m], 0.f);
            if (lane < H) g_x2[(size_t)(base + m) * H + lane] = o2[m];
        }
        if (lane < H) {
#pragma unroll
            for (int m = 0; m < 8; ++m) lbc[w][lane][m] = o2[m];
        }
        // phase 3: xl = x2 @ Wm via LDS broadcast
        float xl[8];
#pragma unroll
        for (int m = 0; m < 8; ++m) xl[m] = 0.f;
#pragma unroll 1
        for (int k = 0; k < H; ++k) {
            float wv = Wm[k * H + lj];
            float4 o0 = *(const float4*)&lbc[w][k][0];
            float4 o1 = *(const float4*)&lbc[w][k][4];
            xl[0] = fmaf(o0.x, wv, xl[0]); xl[1] = fmaf(o0.y, wv, xl[1]);
            xl[2] = fmaf(o0.z, wv, xl[2]); xl[3] = fmaf(o0.w, wv, xl[3]);
            xl[4] = fmaf(o1.x, wv, xl[4]); xl[5] = fmaf(o1.y, wv, xl[5]);
            xl[6] = fmaf(o1.z, wv, xl[6]); xl[7] = fmaf(o1.w, wv, xl[7]);
        }
        float v0, v1, v2, v3, v4, v5, v6, v7;
        v0 = (lane < H) ? xl[0] * asl : 0.f;
        v1 = (lane < H) ? xl[1] * asl : 0.f;
        v2 = (lane < H) ? xl[2] * asl : 0.f;
        v3 = (lane < H) ? xl[3] * asl : 0.f;
        v4 = (lane < H) ? xl[4] * asl : 0.f;
        v5 = (lane < H) ? xl[5] * asl : 0.f;
        v6 = (lane < H) ? xl[6] * asl : 0.f;
        v7 = (lane < H) ? xl[7] * asl : 0.f;
        wave_sum4(v0, v1, v2, v3);
        wave_sum4(v4, v5, v6, v7);
#pragma unroll
        for (int m = 0; m < 8; ++m)
            if (lane < H) g_xl[(size_t)(base + m) * H + lane] = xl[m];
        if (lane == 0) {
            g_al[base + 0] = v0; g_al[base + 1] = v1; g_al[base + 2] = v2; g_al[base + 3] = v3;
            g_al[base + 4] = v4; g_al[base + 5] = v5; g_al[base + 6] = v6; g_al[base + 7] = v7;
        }
    }
}

// ---------------- readout + all 7 timesteps + final linear: wave per graph ----------------
// GRU2 weights cached in LDS as packed bf16 (3 x uint arrays, 31.2 KB); hm/oj via LDS broadcast
__global__ __launch_bounds__(256) void k_mol_all(const float* __restrict__ mb, const float* __restrict__ W2,
                                                 const float* __restrict__ b2, float* __restrict__ dout) {
    __shared__ uint32_t ldsWa[H * H];
    __shared__ uint32_t ldsWb[H * H];
    __shared__ uint32_t ldsWc[H * H];
    __shared__ float lbc[4][52][2];     // per-wave hm/oj broadcast
    int tid = threadIdx.x;
    for (int i = tid; i < H * H; i += 256) {
        const float* s = g_wg2 + (size_t)i * 8;
        ldsWa[i] = f2bf(s[0]) | (f2bf(s[1]) << 16);
        ldsWb[i] = f2bf(s[2]) | (f2bf(s[3]) << 16);
        ldsWc[i] = f2bf(s[4]) | (f2bf(s[5]) << 16);
    }
    __syncthreads();
    int w = tid >> 6;
    int lane = tid & 63;
    int lj = lane < H ? lane : H - 1;
    int b = __builtin_amdgcn_readfirstlane(blockIdx.x * 4 + w);
    int gs = g_gs[b], ge = g_gs[b + 1];
    // readout: out0 = relu(sum x2 rows), unrolled by 2
    float oa = 0.f, ob = 0.f;
    int i = gs;
    for (; i + 2 <= ge; i += 2) {
        oa += g_x2[(size_t)i * H + lane];
        ob += g_x2[(size_t)(i + 1) * H + lane];
    }
    if (i < ge) oa += g_x2[(size_t)i * H + lane];
    float oj = fmaxf(oa + ob, 0.f);
    float wvl = g_wv[lane];
    float mbl = mb[lj];
    const float4* bp = (const float4*)(g_bg2 + lane * 8);
    float4 b0 = bp[0];
    float4 b1v = bp[1];
#pragma unroll 1
    for (int t = 0; t < TSTEPS; ++t) {
        float arb = wave_sum((lane < H) ? oj * wvl : 0.f);
        float sa = 0.f, sb = 0.f, aa = 0.f, ab = 0.f;
        i = gs;
        for (; i + 2 <= ge; i += 2) {
            float ev0 = __expf(lrelu(g_al[i] + arb));
            float ev1 = __expf(lrelu(g_al[i + 1] + arb));
            sa += ev0; sb += ev1;
            aa = fmaf(ev0, g_xl[(size_t)i * H + lane], aa);
            ab = fmaf(ev1, g_xl[(size_t)(i + 1) * H + lane], ab);
        }
        if (i < ge) {
            float ev0 = __expf(lrelu(g_al[i] + arb));
            sa += ev0;
            aa = fmaf(ev0, g_xl[(size_t)i * H + lane], aa);
        }
        float inv = 1.f / (sa + sb + 1e-16f);
        float hm = elu1((aa + ab) * inv + mbl);
        if (lane < H) { lbc[w][lane][0] = hm; lbc[w][lane][1] = oj; }
        float gir = 0, giz = 0, gin = 0, ghr = 0, ghz = 0, ghn = 0;
#pragma unroll 2
        for (int k = 0; k < H; ++k) {
            uint32_t wa = ldsWa[k * H + lj];
            uint32_t wb = ldsWb[k * H + lj];
            uint32_t wc = ldsWc[k * H + lj];
            float2 ho = *(const float2*)&lbc[w][k][0];
            float hmk = ho.x, ok = ho.y;
            gir = fmaf(hmk, bflo(wa), gir); giz = fmaf(hmk, bfhi(wa), giz); gin = fmaf(hmk, bflo(wb), gin);
            ghr = fmaf(ok, bfhi(wb), ghr);  ghz = fmaf(ok, bflo(wc), ghz);  ghn = fmaf(ok, bfhi(wc), ghn);
        }
        float r = sigm(gir + b0.x + ghr + b0.w);
        float z = sigm(giz + b0.y + ghz + b1v.x);
        float nn2 = tanhf(gin + b0.z + r * (ghn + b1v.y));
        oj = fmaxf((1.f - z) * nn2 + z * oj, 0.f);
    }
    float fv = wave_sum((lane < H) ? oj * W2[lj] : 0.f);
    if (lane == 0) dout[b] = fv + b2[0];
}

extern "C" void kernel_launch(void* const* d_in, const int* in_sizes, int n_in,
                              void* d_out, int out_size, void* d_ws, size_t ws_size,
                              hipStream_t stream) {
    const float* x     = (const float*)d_in[0];
    const int*   ei    = (const int*)d_in[1];
    const float* ea    = (const float*)d_in[2];
    const int*   batch = (const int*)d_in[3];
    const float* W1    = (const float*)d_in[4];
    const float* b1    = (const float*)d_in[5];
    const float* We1   = (const float*)d_in[6];
    const float* attl  = (const float*)d_in[7];
    const float* attr_ = (const float*)d_in[8];
    const float* We2   = (const float*)d_in[9];
    const float* gb    = (const float*)d_in[10];
    const float* Wm    = (const float*)d_in[15];
    const float* asrc  = (const float*)d_in[16];
    const float* adst  = (const float*)d_in[17];
    const float* mb    = (const float*)d_in[18];
    const float* W2    = (const float*)d_in[23];
    const float* b2    = (const float*)d_in[24];
    float* dout = (float*)d_out;

    // CSR build + graph offsets
    k_init<<<SCAN_B, 256, 0, stream>>>(batch);
    k_count<<<NE / 256, 256, 0, stream>>>(ei);
    k_scan1<<<SCAN_B, 256, 0, stream>>>();
    k_scan2<<<1, 512, 0, stream>>>();
    k_scan3<<<SCAN_B, 256, 0, stream>>>();
    k_fill<<<NE / 256, 256, 0, stream>>>(ei, ea);

    // weight prep (both GRUs + wv fused)
    k_prep<<<(2 * H * H + 64 + 255) / 256, 256, 0, stream>>>(
        (const float*)d_in[11], (const float*)d_in[12], (const float*)d_in[13], (const float*)d_in[14],
        (const float*)d_in[19], (const float*)d_in[20], (const float*)d_in[21], (const float*)d_in[22],
        Wm, adst);

    // main pipeline
    k_lin1<<<(NN + 255) / 256, 256, 0, stream>>>(x, W1, b1, attr_, We1);
    k_gate<<<NN / 4, 256, 0, stream>>>(We1, attl);
    k_gategru<<<GG_BLOCKS, 256, 0, stream>>>(We2, gb, Wm, asrc);
    k_mol_all<<<NB / 4, 256, 0, stream>>>(mb, W2, b2, dout);
}

// Round 14
// 656.818 us; speedup vs baseline: 1.0039x; 1.0039x over previous
//
#include <hip/hip_runtime.h>
#include <stdint.h>

#define NN 100000
#define NE 1600000
#define NB 4096
#define FIN 92
#define H 51
#define H3 153
#define TSTEPS 7
#define SCAN_B 391   // ceil(NN/256)
#define GG_BLOCKS 768
#define GG_CHUNKS (NN / 32)   // 3125

// ---------------- static device workspace (BSS; no hipMalloc) ----------------
__device__ __align__(16) float g_x1[(size_t)NN * 52 + 64];   // lrelu(x@W1+b1), stride 52 (pad=0)
__device__ __align__(16) unsigned short g_pb[(size_t)NN * 52 + 64]; // x1 @ We1x, bf16
__device__ float g_xr[NN];                     // x1 @ att_r
__device__ float g_agg[(size_t)NN * H + 64];   // softmax-weighted sum of lrelu(xe) per dst
__device__ float g_x2[(size_t)NN * H + 64];    // node state after GRU1 + relu
__device__ float g_xl[(size_t)NN * H + 64];    // x2 @ Wm
__device__ float g_al[NN];                     // xl @ att_src
__device__ int   g_gs[NB + 2];                 // graph start offsets (batch is sorted)
__device__ float g_wg1[H * H * 8];             // GRU1 weights interleaved [k][j][8]
__device__ float g_bg1[64 * 8];
__device__ float g_wg2[H * H * 8];
__device__ float g_bg2[64 * 8];
__device__ float g_wv[64];                     // Wm @ att_dst
// CSR scratch
__device__ int   g_cnt[NN];
__device__ int   g_rp[NN + 1];
__device__ int   g_cur[NN];
__device__ int   g_src[NE + 4];                // src node id, grouped by dst
__device__ __align__(16) float g_eac[(size_t)NE * 12 + 16];  // edge_attr in CSR order, 12-float rows
__device__ int   g_bsum[512];
__device__ int   g_boff[512];

__device__ __forceinline__ float lrelu(float v) { return v > 0.f ? v : 0.01f * v; }
__device__ __forceinline__ float elu1(float v) { return v > 0.f ? v : expm1f(v); }
__device__ __forceinline__ float sigm(float v) { return 1.f / (1.f + __expf(-v)); }

__device__ __forceinline__ float bflo(uint32_t w) { union { uint32_t u; float f; } c; c.u = w << 16; return c.f; }
__device__ __forceinline__ float bfhi(uint32_t w) { union { uint32_t u; float f; } c; c.u = w & 0xffff0000u; return c.f; }
// RNE float->bf16 (returned in low 16 bits)
__device__ __forceinline__ uint32_t f2bf(float f) {
    uint32_t u = __float_as_uint(f);
    return (u + 0x7FFFu + ((u >> 16) & 1u)) >> 16;
}

__device__ __forceinline__ float wave_sum(float v) {
    v += __shfl_xor(v, 32, 64);
    v += __shfl_xor(v, 16, 64);
    v += __shfl_xor(v, 8, 64);
    v += __shfl_xor(v, 4, 64);
    v += __shfl_xor(v, 2, 64);
    v += __shfl_xor(v, 1, 64);
    return v;
}
__device__ __forceinline__ void wave_sum4(float& a, float& b, float& c, float& d) {
    a += __shfl_xor(a, 32, 64); b += __shfl_xor(b, 32, 64); c += __shfl_xor(c, 32, 64); d += __shfl_xor(d, 32, 64);
    a += __shfl_xor(a, 16, 64); b += __shfl_xor(b, 16, 64); c += __shfl_xor(c, 16, 64); d += __shfl_xor(d, 16, 64);
    a += __shfl_xor(a, 8, 64);  b += __shfl_xor(b, 8, 64);  c += __shfl_xor(c, 8, 64);  d += __shfl_xor(d, 8, 64);
    a += __shfl_xor(a, 4, 64);  b += __shfl_xor(b, 4, 64);  c += __shfl_xor(c, 4, 64);  d += __shfl_xor(d, 4, 64);
    a += __shfl_xor(a, 2, 64);  b += __shfl_xor(b, 2, 64);  c += __shfl_xor(c, 2, 64);  d += __shfl_xor(d, 2, 64);
    a += __shfl_xor(a, 1, 64);  b += __shfl_xor(b, 1, 64);  c += __shfl_xor(c, 1, 64);  d += __shfl_xor(d, 1, 64);
}

// dot4 helper — plain inline function, immune to macro member-name capture
__device__ __forceinline__ float d4(float acc, float4 t, float4 wv) {
    return fmaf(t.x, wv.x, fmaf(t.y, wv.y, fmaf(t.z, wv.z, fmaf(t.w, wv.w, acc))));
}

// ---------------- prep ----------------
// zero histogram + graph-start offsets, one launch
__global__ __launch_bounds__(256) void k_init(const int* __restrict__ batch) {
    int n = blockIdx.x * 256 + threadIdx.x;
    if (n >= NN) return;
    g_cnt[n] = 0;
    int bn = batch[n];
    int bp = (n == 0) ? -1 : batch[n - 1];
    for (int b = bp + 1; b <= bn; ++b) g_gs[b] = n;
    if (n == NN - 1) for (int b = bn + 1; b <= NB; ++b) g_gs[b] = NN;
}

// pack both GRUs + wv in one launch
__global__ void k_prep(const float* __restrict__ Wih1, const float* __restrict__ bih1,
                       const float* __restrict__ Whh1, const float* __restrict__ bhh1,
                       const float* __restrict__ Wih2, const float* __restrict__ bih2,
                       const float* __restrict__ Whh2, const float* __restrict__ bhh2,
                       const float* __restrict__ Wm, const float* __restrict__ ad) {
    int id = blockIdx.x * 256 + threadIdx.x;
    int which = 0;
    const float *Wih, *bih, *Whh, *bhh;
    if (id < H * H) {
        which = 0; Wih = Wih1; bih = bih1; Whh = Whh1; bhh = bhh1;
    } else if (id < 2 * H * H) {
        which = 1; id -= H * H; Wih = Wih2; bih = bih2; Whh = Whh2; bhh = bhh2;
    } else {
        int k = id - 2 * H * H;
        if (k < 64) {
            float a = 0.f;
            if (k < H) for (int j = 0; j < H; ++j) a = fmaf(Wm[k * H + j], ad[j], a);
            g_wv[k] = a;
        }
        return;
    }
    float* Wg = which ? g_wg2 : g_wg1;
    float* bg = which ? g_bg2 : g_bg1;
    int k = id / H, j = id - k * H;
    float* o = Wg + (size_t)id * 8;
    o[0] = Wih[k * H3 + j];
    o[1] = Wih[k * H3 + H + j];
    o[2] = Wih[k * H3 + 2 * H + j];
    o[3] = Whh[k * H3 + j];
    o[4] = Whh[k * H3 + H + j];
    o[5] = Whh[k * H3 + 2 * H + j];
    o[6] = 0.f; o[7] = 0.f;
    if (id < H) {
        float* ob = bg + (size_t)id * 8;
        ob[0] = bih[id]; ob[1] = bih[H + id]; ob[2] = bih[2 * H + id];
        ob[3] = bhh[id]; ob[4] = bhh[H + id]; ob[5] = bhh[2 * H + id];
        ob[6] = 0.f; ob[7] = 0.f;
    }
}

// ---------------- CSR build ----------------
__global__ __launch_bounds__(256) void k_count(const int* __restrict__ ei) {
    int e = blockIdx.x * 256 + threadIdx.x;
    if (e >= NE) return;
    atomicAdd(&g_cnt[ei[NE + e]], 1);
}

__global__ __launch_bounds__(256) void k_scan1() {
    __shared__ int sm[256];
    int tid = threadIdx.x;
    int i = blockIdx.x * 256 + tid;
    sm[tid] = (i < NN) ? g_cnt[i] : 0;
    __syncthreads();
#pragma unroll
    for (int off = 1; off < 256; off <<= 1) {
        int t = (tid >= off) ? sm[tid - off] : 0;
        __syncthreads();
        sm[tid] += t;
        __syncthreads();
    }
    if (i < NN) g_rp[i + 1] = sm[tid];
    if (tid == 255) g_bsum[blockIdx.x] = sm[255];
}

__global__ void k_scan2() {
    __shared__ int sm[512];
    int tid = threadIdx.x;
    sm[tid] = (tid < SCAN_B) ? g_bsum[tid] : 0;
    __syncthreads();
#pragma unroll
    for (int off = 1; off < 512; off <<= 1) {
        int t = (tid >= off) ? sm[tid - off] : 0;
        __syncthreads();
        sm[tid] += t;
        __syncthreads();
    }
    if (tid < SCAN_B) g_boff[tid] = (tid == 0) ? 0 : sm[tid - 1];
}

__global__ __launch_bounds__(256) void k_scan3() {
    int i = blockIdx.x * 256 + threadIdx.x;
    if (i >= NN) return;
    int v = g_rp[i + 1] + g_boff[blockIdx.x];
    g_rp[i + 1] = v;
    if (i == 0) { g_rp[0] = 0; g_cur[0] = 0; }
    if (i + 1 < NN) g_cur[i + 1] = v;
}

__global__ __launch_bounds__(256) void k_fill(const int* __restrict__ ei, const float* __restrict__ ea) {
    int e = blockIdx.x * 256 + threadIdx.x;
    if (e >= NE) return;
    int d = ei[NE + e];
    int pos = atomicAdd(&g_cur[d], 1);
    g_src[pos] = ei[e];
    const float2* s2 = (const float2*)(ea + (size_t)e * 10);
    float2 v0 = s2[0], v1 = s2[1], v2 = s2[2], v3 = s2[3], v4 = s2[4];
    float2* d2 = (float2*)(g_eac + (size_t)pos * 12);
    d2[0] = v0; d2[1] = v1; d2[2] = v2; d2[3] = v3; d2[4] = v4;
    d2[5] = make_float2(0.f, 0.f);
}

// ---------------- lin1 (+P fused): x1 = lrelu(x@W1+b1), xr = x1@att_r, P(bf16) = x1@We1x ----------------
__global__ __launch_bounds__(256, 3) void k_lin1(const float* __restrict__ x, const float* __restrict__ W1,
                                                 const float* __restrict__ b1, const float* __restrict__ attr_,
                                                 const float* __restrict__ We1) {
    int n = blockIdx.x * 256 + threadIdx.x;
    if (n >= NN) return;
    const float4* xq4 = (const float4*)(x + (size_t)n * FIN);
    float acc[H];
#pragma unroll
    for (int h = 0; h < H; ++h) acc[h] = 0.f;
#pragma unroll 1
    for (int q = 0; q < FIN / 4; ++q) {
        float4 v = xq4[q];
        const float* wr = W1 + (4 * q) * H;
#pragma unroll
        for (int h = 0; h < H; ++h)
            acc[h] = fmaf(v.x, wr[h], fmaf(v.y, wr[H + h], fmaf(v.z, wr[2 * H + h], fmaf(v.w, wr[3 * H + h], acc[h]))));
    }
    float xrv = 0.f;
    float* xo = g_x1 + (size_t)n * 52;
#pragma unroll
    for (int h = 0; h < H; ++h) {
        float v = lrelu(acc[h] + b1[h]);
        acc[h] = v;            // keep activated row in registers for the P pass
        xo[h] = v;
        xrv = fmaf(v, attr_[h], xrv);
    }
    xo[H] = 0.f;
    g_xr[n] = xrv;
    // P row (bf16): p[h] = sum_k acc[k] * We1[k*H+h]
    unsigned short* po = g_pb + (size_t)n * 52;
#pragma unroll 1
    for (int h = 0; h < H; ++h) {
        float ph = 0.f;
#pragma unroll
        for (int k = 0; k < H; ++k) ph = fmaf(acc[k], We1[k * H + h], ph);
        po[h] = (unsigned short)f2bf(ph);
    }
    po[H] = 0;
}

// ---------------- GATEConv: wave per dst node, lane = channel; bf16 P gather; 1-deep prefetch ----------------
#define MKE(q) make_float4( \
    (4*(q)+0) < 10 ? We1[(51 + 4*(q)+0) * H + lj] : 0.f, \
    (4*(q)+1) < 10 ? We1[(51 + 4*(q)+1) * H + lj] : 0.f, \
    (4*(q)+2) < 10 ? We1[(51 + 4*(q)+2) * H + lj] : 0.f, \
    (4*(q)+3) < 10 ? We1[(51 + 4*(q)+3) * H + lj] : 0.f)

__global__ __launch_bounds__(256, 4) void k_gate(const float* __restrict__ We1, const float* __restrict__ attl) {
    int lane = threadIdx.x & 63;
    int lj = lane < H ? lane : H - 1;
    int n = __builtin_amdgcn_readfirstlane(blockIdx.x * 4 + (threadIdx.x >> 6));
    float4 eq0 = MKE(0), eq1 = MKE(1), eq2 = MKE(2);
    float attlv = attl[lj];
    float xrd = g_xr[n];
    int rs = g_rp[n], re = g_rp[n + 1];
    float accH = 0.f, den = 0.f;
    int nb = (re - rs) >> 2;
    int idx = rs;
    float pv0 = 0.f, pv1 = 0.f, pv2 = 0.f, pv3 = 0.f;
    if (nb > 0) {
        int s0 = __builtin_amdgcn_readfirstlane(g_src[idx]);
        int s1 = __builtin_amdgcn_readfirstlane(g_src[idx + 1]);
        int s2 = __builtin_amdgcn_readfirstlane(g_src[idx + 2]);
        int s3 = __builtin_amdgcn_readfirstlane(g_src[idx + 3]);
        pv0 = bflo(g_pb[(size_t)s0 * 52 + lane]);
        pv1 = bflo(g_pb[(size_t)s1 * 52 + lane]);
        pv2 = bflo(g_pb[(size_t)s2 * 52 + lane]);
        pv3 = bflo(g_pb[(size_t)s3 * 52 + lane]);
    }
#pragma unroll 1
    for (int blk = 0; blk < nb; ++blk) {
        int ci = idx;
        float cp0 = pv0, cp1 = pv1, cp2 = pv2, cp3 = pv3;
        idx += 4;
        if (blk + 1 < nb) {   // prefetch next block's P rows while computing this one
            int s0 = __builtin_amdgcn_readfirstlane(g_src[idx]);
            int s1 = __builtin_amdgcn_readfirstlane(g_src[idx + 1]);
            int s2 = __builtin_amdgcn_readfirstlane(g_src[idx + 2]);
            int s3 = __builtin_amdgcn_readfirstlane(g_src[idx + 3]);
            pv0 = bflo(g_pb[(size_t)s0 * 52 + lane]);
            pv1 = bflo(g_pb[(size_t)s1 * 52 + lane]);
            pv2 = bflo(g_pb[(size_t)s2 * 52 + lane]);
            pv3 = bflo(g_pb[(size_t)s3 * 52 + lane]);
        }
        const float4* ep0 = (const float4*)(g_eac + (size_t)ci * 12);
        const float4* ep1 = (const float4*)(g_eac + (size_t)(ci + 1) * 12);
        const float4* ep2 = (const float4*)(g_eac + (size_t)(ci + 2) * 12);
        const float4* ep3 = (const float4*)(g_eac + (size_t)(ci + 3) * 12);
        float xe0 = cp0, xe1 = cp1, xe2 = cp2, xe3 = cp3;
        xe0 = d4(xe0, ep0[0], eq0); xe0 = d4(xe0, ep0[1], eq1); xe0 = d4(xe0, ep0[2], eq2);
        xe1 = d4(xe1, ep1[0], eq0); xe1 = d4(xe1, ep1[1], eq1); xe1 = d4(xe1, ep1[2], eq2);
        xe2 = d4(xe2, ep2[0], eq0); xe2 = d4(xe2, ep2[1], eq1); xe2 = d4(xe2, ep2[2], eq2);
        xe3 = d4(xe3, ep3[0], eq0); xe3 = d4(xe3, ep3[1], eq1); xe3 = d4(xe3, ep3[2], eq2);
        float l0 = lrelu(xe0), l1 = lrelu(xe1), l2 = lrelu(xe2), l3 = lrelu(xe3);
        float p0 = (lane < H) ? l0 * attlv : 0.f;
        float p1 = (lane < H) ? l1 * attlv : 0.f;
        float p2 = (lane < H) ? l2 * attlv : 0.f;
        float p3 = (lane < H) ? l3 * attlv : 0.f;
        wave_sum4(p0, p1, p2, p3);
        float e0 = __expf(lrelu(p0 + xrd));
        float e1 = __expf(lrelu(p1 + xrd));
        float e2 = __expf(lrelu(p2 + xrd));
        float e3 = __expf(lrelu(p3 + xrd));
        accH = fmaf(e0, l0, accH); den += e0;
        accH = fmaf(e1, l1, accH); den += e1;
        accH = fmaf(e2, l2, accH); den += e2;
        accH = fmaf(e3, l3, accH); den += e3;
    }
    for (; idx < re; ++idx) {
        int s0 = __builtin_amdgcn_readfirstlane(g_src[idx]);
        float pvs = bflo(g_pb[(size_t)s0 * 52 + lane]);
        const float4* ep0 = (const float4*)(g_eac + (size_t)idx * 12);
        float xe0 = pvs;
        xe0 = d4(xe0, ep0[0], eq0); xe0 = d4(xe0, ep0[1], eq1); xe0 = d4(xe0, ep0[2], eq2);
        float l0 = lrelu(xe0);
        float a0 = wave_sum((lane < H) ? l0 * attlv : 0.f);
        float e0 = __expf(lrelu(a0 + xrd));
        accH = fmaf(e0, l0, accH); den += e0;
    }
    if (lane < H) g_agg[(size_t)n * H + lane] = accH / (den + 1e-16f);
}

// ---------------- gate(We2) + GRU1 + xl/al fused: persistent blocks ----------------
// All broadcasts (agg, x, hb, o2) go through per-wave LDS transpose buffers — no s_loads in hot loops.
__global__ __launch_bounds__(256) void k_gategru(const float* __restrict__ We2, const float* __restrict__ gb,
                                                 const float* __restrict__ Wm, const float* __restrict__ asrc) {
    __shared__ uint32_t wA[H * H];
    __shared__ uint32_t wB[H * H];
    __shared__ uint32_t wC[H * H];
    __shared__ float lA[4][52][8];   // agg transpose
    __shared__ float lX[4][52][8];   // x1 transpose
    __shared__ float lH[4][52][8];   // hb, then o2
    int tid = threadIdx.x;
    for (int i = tid; i < H * H; i += 256) {
        const float* s = g_wg1 + (size_t)i * 8;
        wA[i] = f2bf(s[0]) | (f2bf(s[1]) << 16);
        wB[i] = f2bf(s[2]) | (f2bf(s[3]) << 16);
        wC[i] = f2bf(s[4]) | (f2bf(s[5]) << 16);
    }
    __syncthreads();
    int w = tid >> 6;
    int lane = tid & 63;
    int lj = lane < H ? lane : H - 1;
    const float4* bp = (const float4*)(g_bg1 + lane * 8);
    float4 b0 = bp[0];
    float4 b1v = bp[1];
    float gbl = gb[lj];
    float asl = asrc[lj];
#pragma unroll 1
    for (int chunk = blockIdx.x; chunk < GG_CHUNKS; chunk += GG_BLOCKS) {
        int base = __builtin_amdgcn_readfirstlane(chunk * 32 + w * 8);
        float xj[8], ag[8];
#pragma unroll
        for (int m = 0; m < 8; ++m) {
            xj[m] = g_x1[(size_t)(base + m) * 52 + lane];
            ag[m] = g_agg[(size_t)(base + m) * H + lane];
        }
        if (lane < H) {
#pragma unroll
            for (int m = 0; m < 8; ++m) { lA[w][lane][m] = ag[m]; lX[w][lane][m] = xj[m]; }
        }
        // phase 1: hb = elu(agg @ We2 + gb); agg via LDS broadcast
        float ac[8];
#pragma unroll
        for (int m = 0; m < 8; ++m) ac[m] = 0.f;
#pragma unroll 1
        for (int k = 0; k < H; ++k) {
            float wv = We2[k * H + lj];
            float4 a0 = *(const float4*)&lA[w][k][0];
            float4 a1 = *(const float4*)&lA[w][k][4];
            ac[0] = fmaf(a0.x, wv, ac[0]); ac[1] = fmaf(a0.y, wv, ac[1]);
            ac[2] = fmaf(a0.z, wv, ac[2]); ac[3] = fmaf(a0.w, wv, ac[3]);
            ac[4] = fmaf(a1.x, wv, ac[4]); ac[5] = fmaf(a1.y, wv, ac[5]);
            ac[6] = fmaf(a1.z, wv, ac[6]); ac[7] = fmaf(a1.w, wv, ac[7]);
        }
        float hb[8];
#pragma unroll
        for (int m = 0; m < 8; ++m) hb[m] = elu1(ac[m] + gbl);
        if (lane < H) {
#pragma unroll
            for (int m = 0; m < 8; ++m) lH[w][lane][m] = hb[m];
        }
        // phase 2: GRU1 — weights LDS bf16, hb/x via LDS broadcast
        float gir[8], giz[8], gin[8], ghr[8], ghz[8], ghn[8];
#pragma unroll
        for (int m = 0; m < 8; ++m) { gir[m] = 0; giz[m] = 0; gin[m] = 0; ghr[m] = 0; ghz[m] = 0; ghn[m] = 0; }
#pragma unroll 1
        for (int k = 0; k < H; ++k) {
            uint32_t wa = wA[k * H + lj];
            uint32_t wb = wB[k * H + lj];
            uint32_t wc = wC[k * H + lj];
            float w0x = bflo(wa), w0y = bfhi(wa), w0z = bflo(wb);
            float w0w = bfhi(wb), w1x = bflo(wc), w1y = bfhi(wc);
            float4 h0 = *(const float4*)&lH[w][k][0];
            float4 h1 = *(const float4*)&lH[w][k][4];
            float4 x0 = *(const float4*)&lX[w][k][0];
            float4 x1v = *(const float4*)&lX[w][k][4];
            float hk[8] = { h0.x, h0.y, h0.z, h0.w, h1.x, h1.y, h1.z, h1.w };
            float xk[8] = { x0.x, x0.y, x0.z, x0.w, x1v.x, x1v.y, x1v.z, x1v.w };
#pragma unroll
            for (int m = 0; m < 8; ++m) {
                gir[m] = fmaf(hk[m], w0x, gir[m]); giz[m] = fmaf(hk[m], w0y, giz[m]); gin[m] = fmaf(hk[m], w0z, gin[m]);
                ghr[m] = fmaf(xk[m], w0w, ghr[m]); ghz[m] = fmaf(xk[m], w1x, ghz[m]); ghn[m] = fmaf(xk[m], w1y, ghn[m]);
            }
        }
        float o2[8];
#pragma unroll
        for (int m = 0; m < 8; ++m) {
            float r = sigm(gir[m] + b0.x + ghr[m] + b0.w);
            float z = sigm(giz[m] + b0.y + ghz[m] + b1v.x);
            float nn2 = tanhf(gin[m] + b0.z + r * (ghn[m] + b1v.y));
            o2[m] = fmaxf((1.f - z) * nn2 + z * xj[m], 0.f);
            if (lane < H) g_x2[(size_t)(base + m) * H + lane] = o2[m];
        }
        if (lane < H) {
#pragma unroll
            for (int m = 0; m < 8; ++m) lH[w][lane][m] = o2[m];
        }
        // phase 3: xl = x2 @ Wm via LDS broadcast
        float xl[8];
#pragma unroll
        for (int m = 0; m < 8; ++m) xl[m] = 0.f;
#pragma unroll 1
        for (int k = 0; k < H; ++k) {
            float wv = Wm[k * H + lj];
            float4 o0 = *(const float4*)&lH[w][k][0];
            float4 o1 = *(const float4*)&lH[w][k][4];
            xl[0] = fmaf(o0.x, wv, xl[0]); xl[1] = fmaf(o0.y, wv, xl[1]);
            xl[2] = fmaf(o0.z, wv, xl[2]); xl[3] = fmaf(o0.w, wv, xl[3]);
            xl[4] = fmaf(o1.x, wv, xl[4]); xl[5] = fmaf(o1.y, wv, xl[5]);
            xl[6] = fmaf(o1.z, wv, xl[6]); xl[7] = fmaf(o1.w, wv, xl[7]);
        }
        float v0, v1, v2, v3, v4, v5, v6, v7;
        v0 = (lane < H) ? xl[0] * asl : 0.f;
        v1 = (lane < H) ? xl[1] * asl : 0.f;
        v2 = (lane < H) ? xl[2] * asl : 0.f;
        v3 = (lane < H) ? xl[3] * asl : 0.f;
        v4 = (lane < H) ? xl[4] * asl : 0.f;
        v5 = (lane < H) ? xl[5] * asl : 0.f;
        v6 = (lane < H) ? xl[6] * asl : 0.f;
        v7 = (lane < H) ? xl[7] * asl : 0.f;
        wave_sum4(v0, v1, v2, v3);
        wave_sum4(v4, v5, v6, v7);
#pragma unroll
        for (int m = 0; m < 8; ++m)
            if (lane < H) g_xl[(size_t)(base + m) * H + lane] = xl[m];
        if (lane == 0) {
            g_al[base + 0] = v0; g_al[base + 1] = v1; g_al[base + 2] = v2; g_al[base + 3] = v3;
            g_al[base + 4] = v4; g_al[base + 5] = v5; g_al[base + 6] = v6; g_al[base + 7] = v7;
        }
    }
}

// ---------------- readout + all 7 timesteps + final linear: wave per graph ----------------
__global__ __launch_bounds__(256) void k_mol_all(const float* __restrict__ mb, const float* __restrict__ W2,
                                                 const float* __restrict__ b2, float* __restrict__ dout) {
    __shared__ uint32_t ldsWa[H * H];
    __shared__ uint32_t ldsWb[H * H];
    __shared__ uint32_t ldsWc[H * H];
    __shared__ float lbc[4][52][2];     // per-wave hm/oj broadcast
    int tid = threadIdx.x;
    for (int i = tid; i < H * H; i += 256) {
        const float* s = g_wg2 + (size_t)i * 8;
        ldsWa[i] = f2bf(s[0]) | (f2bf(s[1]) << 16);
        ldsWb[i] = f2bf(s[2]) | (f2bf(s[3]) << 16);
        ldsWc[i] = f2bf(s[4]) | (f2bf(s[5]) << 16);
    }
    __syncthreads();
    int w = tid >> 6;
    int lane = tid & 63;
    int lj = lane < H ? lane : H - 1;
    int b = __builtin_amdgcn_readfirstlane(blockIdx.x * 4 + w);
    int gs = g_gs[b], ge = g_gs[b + 1];
    float oa = 0.f, ob = 0.f;
    int i = gs;
    for (; i + 2 <= ge; i += 2) {
        oa += g_x2[(size_t)i * H + lane];
        ob += g_x2[(size_t)(i + 1) * H + lane];
    }
    if (i < ge) oa += g_x2[(size_t)i * H + lane];
    float oj = fmaxf(oa + ob, 0.f);
    float wvl = g_wv[lane];
    float mbl = mb[lj];
    const float4* bp = (const float4*)(g_bg2 + lane * 8);
    float4 b0 = bp[0];
    float4 b1v = bp[1];
#pragma unroll 1
    for (int t = 0; t < TSTEPS; ++t) {
        float arb = wave_sum((lane < H) ? oj * wvl : 0.f);
        float sa = 0.f, sb = 0.f, aa = 0.f, ab = 0.f;
        i = gs;
        for (; i + 2 <= ge; i += 2) {
            float ev0 = __expf(lrelu(g_al[i] + arb));
            float ev1 = __expf(lrelu(g_al[i + 1] + arb));
            sa += ev0; sb += ev1;
            aa = fmaf(ev0, g_xl[(size_t)i * H + lane], aa);
            ab = fmaf(ev1, g_xl[(size_t)(i + 1) * H + lane], ab);
        }
        if (i < ge) {
            float ev0 = __expf(lrelu(g_al[i] + arb));
            sa += ev0;
            aa = fmaf(ev0, g_xl[(size_t)i * H + lane], aa);
        }
        float inv = 1.f / (sa + sb + 1e-16f);
        float hm = elu1((aa + ab) * inv + mbl);
        if (lane < H) { lbc[w][lane][0] = hm; lbc[w][lane][1] = oj; }
        float gir = 0, giz = 0, gin = 0, ghr = 0, ghz = 0, ghn = 0;
#pragma unroll 2
        for (int k = 0; k < H; ++k) {
            uint32_t wa = ldsWa[k * H + lj];
            uint32_t wb = ldsWb[k * H + lj];
            uint32_t wc = ldsWc[k * H + lj];
            float2 ho = *(const float2*)&lbc[w][k][0];
            float hmk = ho.x, ok = ho.y;
            gir = fmaf(hmk, bflo(wa), gir); giz = fmaf(hmk, bfhi(wa), giz); gin = fmaf(hmk, bflo(wb), gin);
            ghr = fmaf(ok, bfhi(wb), ghr);  ghz = fmaf(ok, bflo(wc), ghz);  ghn = fmaf(ok, bfhi(wc), ghn);
        }
        float r = sigm(gir + b0.x + ghr + b0.w);
        float z = sigm(giz + b0.y + ghz + b1v.x);
        float nn2 = tanhf(gin + b0.z + r * (ghn + b1v.y));
        oj = fmaxf((1.f - z) * nn2 + z * oj, 0.f);
    }
    float fv = wave_sum((lane < H) ? oj * W2[lj] : 0.f);
    if (lane == 0) dout[b] = fv + b2[0];
}

extern "C" void kernel_launch(void* const* d_in, const int* in_sizes, int n_in,
                              void* d_out, int out_size, void* d_ws, size_t ws_size,
                              hipStream_t stream) {
    const float* x     = (const float*)d_in[0];
    const int*   ei    = (const int*)d_in[1];
    const float* ea    = (const float*)d_in[2];
    const int*   batch = (const int*)d_in[3];
    const float* W1    = (const float*)d_in[4];
    const float* b1    = (const float*)d_in[5];
    const float* We1   = (const float*)d_in[6];
    const float* attl  = (const float*)d_in[7];
    const float* attr_ = (const float*)d_in[8];
    const float* We2   = (const float*)d_in[9];
    const float* gb    = (const float*)d_in[10];
    const float* Wm    = (const float*)d_in[15];
    const float* asrc  = (const float*)d_in[16];
    const float* adst  = (const float*)d_in[17];
    const float* mb    = (const float*)d_in[18];
    const float* W2    = (const float*)d_in[23];
    const float* b2    = (const float*)d_in[24];
    float* dout = (float*)d_out;

    // CSR build + graph offsets
    k_init<<<SCAN_B, 256, 0, stream>>>(batch);
    k_count<<<NE / 256, 256, 0, stream>>>(ei);
    k_scan1<<<SCAN_B, 256, 0, stream>>>();
    k_scan2<<<1, 512, 0, stream>>>();
    k_scan3<<<SCAN_B, 256, 0, stream>>>();
    k_fill<<<NE / 256, 256, 0, stream>>>(ei, ea);

    // weight prep (both GRUs + wv fused)
    k_prep<<<(2 * H * H + 64 + 255) / 256, 256, 0, stream>>>(
        (const float*)d_in[11], (const float*)d_in[12], (const float*)d_in[13], (const float*)d_in[14],
        (const float*)d_in[19], (const float*)d_in[20], (const float*)d_in[21], (const float*)d_in[22],
        Wm, adst);

    // main pipeline
    k_lin1<<<(NN + 255) / 256, 256, 0, stream>>>(x, W1, b1, attr_, We1);
    k_gate<<<NN / 4, 256, 0, stream>>>(We1, attl);
    k_gategru<<<GG_BLOCKS, 256, 0, stream>>>(We2, gb, Wm, asrc);
    k_mol_all<<<NB / 4, 256, 0, stream>>>(mb, W2, b2, dout);
}

// Round 15
// 567.975 us; speedup vs baseline: 1.1609x; 1.1564x over previous
//
#include <hip/hip_runtime.h>
#include <stdint.h>

#define NN 100000
#define NE 1600000
#define NB 4096
#define FIN 92
#define H 51
#define H3 153
#define TSTEPS 7
#define SCAN_B 391   // ceil(NN/256)
#define GG_BLOCKS 768
#define GG_CHUNKS (NN / 32)   // 3125

// ---------------- static device workspace (BSS; no hipMalloc) ----------------
__device__ __align__(16) float g_x1[(size_t)NN * 52 + 64];   // lrelu(x@W1+b1), stride 52 (pad=0)
__device__ __align__(16) unsigned short g_pb[(size_t)NN * 52 + 64]; // x1 @ We1x, bf16
__device__ float g_xr[NN];                     // x1 @ att_r
__device__ float g_agg[(size_t)NN * H + 64];   // softmax-weighted sum of lrelu(xe) per dst
__device__ float g_x2[(size_t)NN * H + 64];    // node state after GRU1 + relu
__device__ float g_xl[(size_t)NN * H + 64];    // x2 @ Wm
__device__ float g_al[NN];                     // xl @ att_src
__device__ int   g_gs[NB + 2];                 // graph start offsets (batch is sorted)
__device__ float g_wg1[H * H * 8];             // GRU1 weights interleaved [k][j][8]
__device__ float g_bg1[64 * 8];
__device__ float g_wg2[H * H * 8];
__device__ float g_bg2[64 * 8];
__device__ float g_wv[64];                     // Wm @ att_dst
// CSR scratch
__device__ int   g_cnt[NN];
__device__ int   g_rp[NN + 1];
__device__ int   g_cur[NN];
__device__ int   g_src[NE + 4];                // src node id, grouped by dst
__device__ __align__(16) uint32_t g_eac[(size_t)NE * 6 + 16];  // edge_attr bf16 in CSR order, 6 dwords/edge
__device__ int   g_bsum[512];
__device__ int   g_boff[512];

__device__ __forceinline__ float lrelu(float v) { return v > 0.f ? v : 0.01f * v; }
__device__ __forceinline__ float elu1(float v) { return v > 0.f ? v : expm1f(v); }
__device__ __forceinline__ float sigm(float v) { return 1.f / (1.f + __expf(-v)); }

__device__ __forceinline__ float bflo(uint32_t w) { union { uint32_t u; float f; } c; c.u = w << 16; return c.f; }
__device__ __forceinline__ float bfhi(uint32_t w) { union { uint32_t u; float f; } c; c.u = w & 0xffff0000u; return c.f; }
// RNE float->bf16 (returned in low 16 bits)
__device__ __forceinline__ uint32_t f2bf(float f) {
    uint32_t u = __float_as_uint(f);
    return (u + 0x7FFFu + ((u >> 16) & 1u)) >> 16;
}

__device__ __forceinline__ float wave_sum(float v) {
    v += __shfl_xor(v, 32, 64);
    v += __shfl_xor(v, 16, 64);
    v += __shfl_xor(v, 8, 64);
    v += __shfl_xor(v, 4, 64);
    v += __shfl_xor(v, 2, 64);
    v += __shfl_xor(v, 1, 64);
    return v;
}
__device__ __forceinline__ void wave_sum4(float& a, float& b, float& c, float& d) {
    a += __shfl_xor(a, 32, 64); b += __shfl_xor(b, 32, 64); c += __shfl_xor(c, 32, 64); d += __shfl_xor(d, 32, 64);
    a += __shfl_xor(a, 16, 64); b += __shfl_xor(b, 16, 64); c += __shfl_xor(c, 16, 64); d += __shfl_xor(d, 16, 64);
    a += __shfl_xor(a, 8, 64);  b += __shfl_xor(b, 8, 64);  c += __shfl_xor(c, 8, 64);  d += __shfl_xor(d, 8, 64);
    a += __shfl_xor(a, 4, 64);  b += __shfl_xor(b, 4, 64);  c += __shfl_xor(c, 4, 64);  d += __shfl_xor(d, 4, 64);
    a += __shfl_xor(a, 2, 64);  b += __shfl_xor(b, 2, 64);  c += __shfl_xor(c, 2, 64);  d += __shfl_xor(d, 2, 64);
    a += __shfl_xor(a, 1, 64);  b += __shfl_xor(b, 1, 64);  c += __shfl_xor(c, 1, 64);  d += __shfl_xor(d, 1, 64);
}

// ---------------- prep ----------------
__global__ __launch_bounds__(256) void k_init(const int* __restrict__ batch) {
    int n = blockIdx.x * 256 + threadIdx.x;
    if (n >= NN) return;
    g_cnt[n] = 0;
    int bn = batch[n];
    int bp = (n == 0) ? -1 : batch[n - 1];
    for (int b = bp + 1; b <= bn; ++b) g_gs[b] = n;
    if (n == NN - 1) for (int b = bn + 1; b <= NB; ++b) g_gs[b] = NN;
}

// pack both GRUs + wv in one launch
__global__ void k_prep(const float* __restrict__ Wih1, const float* __restrict__ bih1,
                       const float* __restrict__ Whh1, const float* __restrict__ bhh1,
                       const float* __restrict__ Wih2, const float* __restrict__ bih2,
                       const float* __restrict__ Whh2, const float* __restrict__ bhh2,
                       const float* __restrict__ Wm, const float* __restrict__ ad) {
    int id = blockIdx.x * 256 + threadIdx.x;
    int which = 0;
    const float *Wih, *bih, *Whh, *bhh;
    if (id < H * H) {
        which = 0; Wih = Wih1; bih = bih1; Whh = Whh1; bhh = bhh1;
    } else if (id < 2 * H * H) {
        which = 1; id -= H * H; Wih = Wih2; bih = bih2; Whh = Whh2; bhh = bhh2;
    } else {
        int k = id - 2 * H * H;
        if (k < 64) {
            float a = 0.f;
            if (k < H) for (int j = 0; j < H; ++j) a = fmaf(Wm[k * H + j], ad[j], a);
            g_wv[k] = a;
        }
        return;
    }
    float* Wg = which ? g_wg2 : g_wg1;
    float* bg = which ? g_bg2 : g_bg1;
    int k = id / H, j = id - k * H;
    float* o = Wg + (size_t)id * 8;
    o[0] = Wih[k * H3 + j];
    o[1] = Wih[k * H3 + H + j];
    o[2] = Wih[k * H3 + 2 * H + j];
    o[3] = Whh[k * H3 + j];
    o[4] = Whh[k * H3 + H + j];
    o[5] = Whh[k * H3 + 2 * H + j];
    o[6] = 0.f; o[7] = 0.f;
    if (id < H) {
        float* ob = bg + (size_t)id * 8;
        ob[0] = bih[id]; ob[1] = bih[H + id]; ob[2] = bih[2 * H + id];
        ob[3] = bhh[id]; ob[4] = bhh[H + id]; ob[5] = bhh[2 * H + id];
        ob[6] = 0.f; ob[7] = 0.f;
    }
}

// ---------------- CSR build ----------------
__global__ __launch_bounds__(256) void k_count(const int* __restrict__ ei) {
    int e = blockIdx.x * 256 + threadIdx.x;
    if (e >= NE) return;
    atomicAdd(&g_cnt[ei[NE + e]], 1);
}

__global__ __launch_bounds__(256) void k_scan1() {
    __shared__ int sm[256];
    int tid = threadIdx.x;
    int i = blockIdx.x * 256 + tid;
    sm[tid] = (i < NN) ? g_cnt[i] : 0;
    __syncthreads();
#pragma unroll
    for (int off = 1; off < 256; off <<= 1) {
        int t = (tid >= off) ? sm[tid - off] : 0;
        __syncthreads();
        sm[tid] += t;
        __syncthreads();
    }
    if (i < NN) g_rp[i + 1] = sm[tid];
    if (tid == 255) g_bsum[blockIdx.x] = sm[255];
}

__global__ void k_scan2() {
    __shared__ int sm[512];
    int tid = threadIdx.x;
    sm[tid] = (tid < SCAN_B) ? g_bsum[tid] : 0;
    __syncthreads();
#pragma unroll
    for (int off = 1; off < 512; off <<= 1) {
        int t = (tid >= off) ? sm[tid - off] : 0;
        __syncthreads();
        sm[tid] += t;
        __syncthreads();
    }
    if (tid < SCAN_B) g_boff[tid] = (tid == 0) ? 0 : sm[tid - 1];
}

__global__ __launch_bounds__(256) void k_scan3() {
    int i = blockIdx.x * 256 + threadIdx.x;
    if (i >= NN) return;
    int v = g_rp[i + 1] + g_boff[blockIdx.x];
    g_rp[i + 1] = v;
    if (i == 0) { g_rp[0] = 0; g_cur[0] = 0; }
    if (i + 1 < NN) g_cur[i + 1] = v;
}

__global__ __launch_bounds__(256) void k_fill(const int* __restrict__ ei, const float* __restrict__ ea) {
    int e = blockIdx.x * 256 + threadIdx.x;
    if (e >= NE) return;
    int d = ei[NE + e];
    int pos = atomicAdd(&g_cur[d], 1);
    g_src[pos] = ei[e];
    const float2* s2 = (const float2*)(ea + (size_t)e * 10);
    float2 v0 = s2[0], v1 = s2[1], v2 = s2[2], v3 = s2[3], v4 = s2[4];
    uint32_t d0 = f2bf(v0.x) | (f2bf(v0.y) << 16);
    uint32_t d1 = f2bf(v1.x) | (f2bf(v1.y) << 16);
    uint32_t d2 = f2bf(v2.x) | (f2bf(v2.y) << 16);
    uint32_t d3 = f2bf(v3.x) | (f2bf(v3.y) << 16);
    uint32_t d4 = f2bf(v4.x) | (f2bf(v4.y) << 16);
    uint2* dp = (uint2*)(g_eac + (size_t)pos * 6);
    dp[0] = make_uint2(d0, d1);
    dp[1] = make_uint2(d2, d3);
    dp[2] = make_uint2(d4, 0u);
}

// ---------------- lin1 (+P fused): x1 = lrelu(x@W1+b1), xr = x1@att_r, P(bf16) = x1@We1x ----------------
__global__ __launch_bounds__(256, 3) void k_lin1(const float* __restrict__ x, const float* __restrict__ W1,
                                                 const float* __restrict__ b1, const float* __restrict__ attr_,
                                                 const float* __restrict__ We1) {
    int n = blockIdx.x * 256 + threadIdx.x;
    if (n >= NN) return;
    const float4* xq4 = (const float4*)(x + (size_t)n * FIN);
    float acc[H];
#pragma unroll
    for (int h = 0; h < H; ++h) acc[h] = 0.f;
#pragma unroll 1
    for (int q = 0; q < FIN / 4; ++q) {
        float4 v = xq4[q];
        const float* wr = W1 + (4 * q) * H;
#pragma unroll
        for (int h = 0; h < H; ++h)
            acc[h] = fmaf(v.x, wr[h], fmaf(v.y, wr[H + h], fmaf(v.z, wr[2 * H + h], fmaf(v.w, wr[3 * H + h], acc[h]))));
    }
    float xrv = 0.f;
    float* xo = g_x1 + (size_t)n * 52;
#pragma unroll
    for (int h = 0; h < H; ++h) {
        float v = lrelu(acc[h] + b1[h]);
        acc[h] = v;            // keep activated row in registers for the P pass
        xo[h] = v;
        xrv = fmaf(v, attr_[h], xrv);
    }
    xo[H] = 0.f;
    g_xr[n] = xrv;
    // P row (bf16): p[h] = sum_k acc[k] * We1[k*H+h]
    unsigned short* po = g_pb + (size_t)n * 52;
#pragma unroll 1
    for (int h = 0; h < H; ++h) {
        float ph = 0.f;
#pragma unroll
        for (int k = 0; k < H; ++k) ph = fmaf(acc[k], We1[k * H + h], ph);
        po[h] = (unsigned short)f2bf(ph);
    }
    po[H] = 0;
}

// ---------------- GATEConv: wave per dst node, lane = channel; bf16 P gather + bf16 eac ----------------
__global__ __launch_bounds__(256, 4) void k_gate(const float* __restrict__ We1, const float* __restrict__ attl) {
    int lane = threadIdx.x & 63;
    int lj = lane < H ? lane : H - 1;
    int n = __builtin_amdgcn_readfirstlane(blockIdx.x * 4 + (threadIdx.x >> 6));
    // 10 ea-part weight values for this lane's channel (rows 51..60 of We1)
    float we0 = We1[(51 + 0) * H + lj], we1 = We1[(51 + 1) * H + lj];
    float we2 = We1[(51 + 2) * H + lj], we3 = We1[(51 + 3) * H + lj];
    float we4 = We1[(51 + 4) * H + lj], we5 = We1[(51 + 5) * H + lj];
    float we6 = We1[(51 + 6) * H + lj], we7 = We1[(51 + 7) * H + lj];
    float we8 = We1[(51 + 8) * H + lj], we9 = We1[(51 + 9) * H + lj];
    float attlv = attl[lj];
    float xrd = g_xr[n];
    int rs = g_rp[n], re = g_rp[n + 1];
    float accH = 0.f, den = 0.f;
    int nb = (re - rs) >> 2;
    int idx = rs;
    float pv0 = 0.f, pv1 = 0.f, pv2 = 0.f, pv3 = 0.f;
    if (nb > 0) {
        int s0 = __builtin_amdgcn_readfirstlane(g_src[idx]);
        int s1 = __builtin_amdgcn_readfirstlane(g_src[idx + 1]);
        int s2 = __builtin_amdgcn_readfirstlane(g_src[idx + 2]);
        int s3 = __builtin_amdgcn_readfirstlane(g_src[idx + 3]);
        pv0 = bflo(g_pb[(size_t)s0 * 52 + lane]);
        pv1 = bflo(g_pb[(size_t)s1 * 52 + lane]);
        pv2 = bflo(g_pb[(size_t)s2 * 52 + lane]);
        pv3 = bflo(g_pb[(size_t)s3 * 52 + lane]);
    }
#pragma unroll 1
    for (int blk = 0; blk < nb; ++blk) {
        int ci = idx;
        float cp0 = pv0, cp1 = pv1, cp2 = pv2, cp3 = pv3;
        idx += 4;
        if (blk + 1 < nb) {   // prefetch next block's P rows while computing this one
            int s0 = __builtin_amdgcn_readfirstlane(g_src[idx]);
            int s1 = __builtin_amdgcn_readfirstlane(g_src[idx + 1]);
            int s2 = __builtin_amdgcn_readfirstlane(g_src[idx + 2]);
            int s3 = __builtin_amdgcn_readfirstlane(g_src[idx + 3]);
            pv0 = bflo(g_pb[(size_t)s0 * 52 + lane]);
            pv1 = bflo(g_pb[(size_t)s1 * 52 + lane]);
            pv2 = bflo(g_pb[(size_t)s2 * 52 + lane]);
            pv3 = bflo(g_pb[(size_t)s3 * 52 + lane]);
        }
        const uint2* ep0 = (const uint2*)(g_eac + (size_t)ci * 6);
        const uint2* ep1 = (const uint2*)(g_eac + (size_t)(ci + 1) * 6);
        const uint2* ep2 = (const uint2*)(g_eac + (size_t)(ci + 2) * 6);
        const uint2* ep3 = (const uint2*)(g_eac + (size_t)(ci + 3) * 6);
        uint2 A0 = ep0[0], B0 = ep0[1], C0 = ep0[2];
        uint2 A1 = ep1[0], B1 = ep1[1], C1 = ep1[2];
        uint2 A2 = ep2[0], B2 = ep2[1], C2 = ep2[2];
        uint2 A3 = ep3[0], B3 = ep3[1], C3 = ep3[2];
        float xe0 = cp0, xe1 = cp1, xe2 = cp2, xe3 = cp3;
        xe0 = fmaf(bflo(A0.x), we0, xe0); xe0 = fmaf(bfhi(A0.x), we1, xe0);
        xe0 = fmaf(bflo(A0.y), we2, xe0); xe0 = fmaf(bfhi(A0.y), we3, xe0);
        xe0 = fmaf(bflo(B0.x), we4, xe0); xe0 = fmaf(bfhi(B0.x), we5, xe0);
        xe0 = fmaf(bflo(B0.y), we6, xe0); xe0 = fmaf(bfhi(B0.y), we7, xe0);
        xe0 = fmaf(bflo(C0.x), we8, xe0); xe0 = fmaf(bfhi(C0.x), we9, xe0);
        xe1 = fmaf(bflo(A1.x), we0, xe1); xe1 = fmaf(bfhi(A1.x), we1, xe1);
        xe1 = fmaf(bflo(A1.y), we2, xe1); xe1 = fmaf(bfhi(A1.y), we3, xe1);
        xe1 = fmaf(bflo(B1.x), we4, xe1); xe1 = fmaf(bfhi(B1.x), we5, xe1);
        xe1 = fmaf(bflo(B1.y), we6, xe1); xe1 = fmaf(bfhi(B1.y), we7, xe1);
        xe1 = fmaf(bflo(C1.x), we8, xe1); xe1 = fmaf(bfhi(C1.x), we9, xe1);
        xe2 = fmaf(bflo(A2.x), we0, xe2); xe2 = fmaf(bfhi(A2.x), we1, xe2);
        xe2 = fmaf(bflo(A2.y), we2, xe2); xe2 = fmaf(bfhi(A2.y), we3, xe2);
        xe2 = fmaf(bflo(B2.x), we4, xe2); xe2 = fmaf(bfhi(B2.x), we5, xe2);
        xe2 = fmaf(bflo(B2.y), we6, xe2); xe2 = fmaf(bfhi(B2.y), we7, xe2);
        xe2 = fmaf(bflo(C2.x), we8, xe2); xe2 = fmaf(bfhi(C2.x), we9, xe2);
        xe3 = fmaf(bflo(A3.x), we0, xe3); xe3 = fmaf(bfhi(A3.x), we1, xe3);
        xe3 = fmaf(bflo(A3.y), we2, xe3); xe3 = fmaf(bfhi(A3.y), we3, xe3);
        xe3 = fmaf(bflo(B3.x), we4, xe3); xe3 = fmaf(bfhi(B3.x), we5, xe3);
        xe3 = fmaf(bflo(B3.y), we6, xe3); xe3 = fmaf(bfhi(B3.y), we7, xe3);
        xe3 = fmaf(bflo(C3.x), we8, xe3); xe3 = fmaf(bfhi(C3.x), we9, xe3);
        float l0 = lrelu(xe0), l1 = lrelu(xe1), l2 = lrelu(xe2), l3 = lrelu(xe3);
        float p0 = (lane < H) ? l0 * attlv : 0.f;
        float p1 = (lane < H) ? l1 * attlv : 0.f;
        float p2 = (lane < H) ? l2 * attlv : 0.f;
        float p3 = (lane < H) ? l3 * attlv : 0.f;
        wave_sum4(p0, p1, p2, p3);
        float e0 = __expf(lrelu(p0 + xrd));
        float e1 = __expf(lrelu(p1 + xrd));
        float e2 = __expf(lrelu(p2 + xrd));
        float e3 = __expf(lrelu(p3 + xrd));
        accH = fmaf(e0, l0, accH); den += e0;
        accH = fmaf(e1, l1, accH); den += e1;
        accH = fmaf(e2, l2, accH); den += e2;
        accH = fmaf(e3, l3, accH); den += e3;
    }
    for (; idx < re; ++idx) {
        int s0 = __builtin_amdgcn_readfirstlane(g_src[idx]);
        float pvs = bflo(g_pb[(size_t)s0 * 52 + lane]);
        const uint2* ep0 = (const uint2*)(g_eac + (size_t)idx * 6);
        uint2 A0 = ep0[0], B0 = ep0[1], C0 = ep0[2];
        float xe0 = pvs;
        xe0 = fmaf(bflo(A0.x), we0, xe0); xe0 = fmaf(bfhi(A0.x), we1, xe0);
        xe0 = fmaf(bflo(A0.y), we2, xe0); xe0 = fmaf(bfhi(A0.y), we3, xe0);
        xe0 = fmaf(bflo(B0.x), we4, xe0); xe0 = fmaf(bfhi(B0.x), we5, xe0);
        xe0 = fmaf(bflo(B0.y), we6, xe0); xe0 = fmaf(bfhi(B0.y), we7, xe0);
        xe0 = fmaf(bflo(C0.x), we8, xe0); xe0 = fmaf(bfhi(C0.x), we9, xe0);
        float l0 = lrelu(xe0);
        float a0 = wave_sum((lane < H) ? l0 * attlv : 0.f);
        float e0 = __expf(lrelu(a0 + xrd));
        accH = fmaf(e0, l0, accH); den += e0;
    }
    if (lane < H) g_agg[(size_t)n * H + lane] = accH / (den + 1e-16f);
}

// ---------------- gate(We2) + GRU1 + xl/al fused: persistent blocks ----------------
__global__ __launch_bounds__(256) void k_gategru(const float* __restrict__ We2, const float* __restrict__ gb,
                                                 const float* __restrict__ Wm, const float* __restrict__ asrc) {
    __shared__ uint32_t wA[H * H];
    __shared__ uint32_t wB[H * H];
    __shared__ uint32_t wC[H * H];
    __shared__ float lA[4][52][8];   // agg transpose
    __shared__ float lX[4][52][8];   // x1 transpose
    __shared__ float lH[4][52][8];   // hb, then o2
    int tid = threadIdx.x;
    for (int i = tid; i < H * H; i += 256) {
        const float* s = g_wg1 + (size_t)i * 8;
        wA[i] = f2bf(s[0]) | (f2bf(s[1]) << 16);
        wB[i] = f2bf(s[2]) | (f2bf(s[3]) << 16);
        wC[i] = f2bf(s[4]) | (f2bf(s[5]) << 16);
    }
    __syncthreads();
    int w = tid >> 6;
    int lane = tid & 63;
    int lj = lane < H ? lane : H - 1;
    const float4* bp = (const float4*)(g_bg1 + lane * 8);
    float4 b0 = bp[0];
    float4 b1v = bp[1];
    float gbl = gb[lj];
    float asl = asrc[lj];
#pragma unroll 1
    for (int chunk = blockIdx.x; chunk < GG_CHUNKS; chunk += GG_BLOCKS) {
        int base = __builtin_amdgcn_readfirstlane(chunk * 32 + w * 8);
        float xj[8], ag[8];
#pragma unroll
        for (int m = 0; m < 8; ++m) {
            xj[m] = g_x1[(size_t)(base + m) * 52 + lane];
            ag[m] = g_agg[(size_t)(base + m) * H + lane];
        }
        if (lane < H) {
#pragma unroll
            for (int m = 0; m < 8; ++m) { lA[w][lane][m] = ag[m]; lX[w][lane][m] = xj[m]; }
        }
        // phase 1: hb = elu(agg @ We2 + gb); agg via LDS broadcast
        float ac[8];
#pragma unroll
        for (int m = 0; m < 8; ++m) ac[m] = 0.f;
#pragma unroll 1
        for (int k = 0; k < H; ++k) {
            float wv = We2[k * H + lj];
            float4 a0 = *(const float4*)&lA[w][k][0];
            float4 a1 = *(const float4*)&lA[w][k][4];
            ac[0] = fmaf(a0.x, wv, ac[0]); ac[1] = fmaf(a0.y, wv, ac[1]);
            ac[2] = fmaf(a0.z, wv, ac[2]); ac[3] = fmaf(a0.w, wv, ac[3]);
            ac[4] = fmaf(a1.x, wv, ac[4]); ac[5] = fmaf(a1.y, wv, ac[5]);
            ac[6] = fmaf(a1.z, wv, ac[6]); ac[7] = fmaf(a1.w, wv, ac[7]);
        }
        float hb[8];
#pragma unroll
        for (int m = 0; m < 8; ++m) hb[m] = elu1(ac[m] + gbl);
        if (lane < H) {
#pragma unroll
            for (int m = 0; m < 8; ++m) lH[w][lane][m] = hb[m];
        }
        // phase 2: GRU1 — weights LDS bf16, hb/x via LDS broadcast
        float gir[8], giz[8], gin[8], ghr[8], ghz[8], ghn[8];
#pragma unroll
        for (int m = 0; m < 8; ++m) { gir[m] = 0; giz[m] = 0; gin[m] = 0; ghr[m] = 0; ghz[m] = 0; ghn[m] = 0; }
#pragma unroll 1
        for (int k = 0; k < H; ++k) {
            uint32_t wa = wA[k * H + lj];
            uint32_t wb = wB[k * H + lj];
            uint32_t wc = wC[k * H + lj];
            float w0x = bflo(wa), w0y = bfhi(wa), w0z = bflo(wb);
            float w0w = bfhi(wb), w1x = bflo(wc), w1y = bfhi(wc);
            float4 h0 = *(const float4*)&lH[w][k][0];
            float4 h1 = *(const float4*)&lH[w][k][4];
            float4 x0 = *(const float4*)&lX[w][k][0];
            float4 x1v = *(const float4*)&lX[w][k][4];
            float hk[8] = { h0.x, h0.y, h0.z, h0.w, h1.x, h1.y, h1.z, h1.w };
            float xk[8] = { x0.x, x0.y, x0.z, x0.w, x1v.x, x1v.y, x1v.z, x1v.w };
#pragma unroll
            for (int m = 0; m < 8; ++m) {
                gir[m] = fmaf(hk[m], w0x, gir[m]); giz[m] = fmaf(hk[m], w0y, giz[m]); gin[m] = fmaf(hk[m], w0z, gin[m]);
                ghr[m] = fmaf(xk[m], w0w, ghr[m]); ghz[m] = fmaf(xk[m], w1x, ghz[m]); ghn[m] = fmaf(xk[m], w1y, ghn[m]);
            }
        }
        float o2[8];
#pragma unroll
        for (int m = 0; m < 8; ++m) {
            float r = sigm(gir[m] + b0.x + ghr[m] + b0.w);
            float z = sigm(giz[m] + b0.y + ghz[m] + b1v.x);
            float nn2 = tanhf(gin[m] + b0.z + r * (ghn[m] + b1v.y));
            o2[m] = fmaxf((1.f - z) * nn2 + z * xj[m], 0.f);
            if (lane < H) g_x2[(size_t)(base + m) * H + lane] = o2[m];
        }
        if (lane < H) {
#pragma unroll
            for (int m = 0; m < 8; ++m) lH[w][lane][m] = o2[m];
        }
        // phase 3: xl = x2 @ Wm via LDS broadcast
        float xl[8];
#pragma unroll
        for (int m = 0; m < 8; ++m) xl[m] = 0.f;
#pragma unroll 1
        for (int k = 0; k < H; ++k) {
            float wv = Wm[k * H + lj];
            float4 o0 = *(const float4*)&lH[w][k][0];
            float4 o1 = *(const float4*)&lH[w][k][4];
            xl[0] = fmaf(o0.x, wv, xl[0]); xl[1] = fmaf(o0.y, wv, xl[1]);
            xl[2] = fmaf(o0.z, wv, xl[2]); xl[3] = fmaf(o0.w, wv, xl[3]);
            xl[4] = fmaf(o1.x, wv, xl[4]); xl[5] = fmaf(o1.y, wv, xl[5]);
            xl[6] = fmaf(o1.z, wv, xl[6]); xl[7] = fmaf(o1.w, wv, xl[7]);
        }
        float v0, v1, v2, v3, v4, v5, v6, v7;
        v0 = (lane < H) ? xl[0] * asl : 0.f;
        v1 = (lane < H) ? xl[1] * asl : 0.f;
        v2 = (lane < H) ? xl[2] * asl : 0.f;
        v3 = (lane < H) ? xl[3] * asl : 0.f;
        v4 = (lane < H) ? xl[4] * asl : 0.f;
        v5 = (lane < H) ? xl[5] * asl : 0.f;
        v6 = (lane < H) ? xl[6] * asl : 0.f;
        v7 = (lane < H) ? xl[7] * asl : 0.f;
        wave_sum4(v0, v1, v2, v3);
        wave_sum4(v4, v5, v6, v7);
#pragma unroll
        for (int m = 0; m < 8; ++m)
            if (lane < H) g_xl[(size_t)(base + m) * H + lane] = xl[m];
        if (lane == 0) {
            g_al[base + 0] = v0; g_al[base + 1] = v1; g_al[base + 2] = v2; g_al[base + 3] = v3;
            g_al[base + 4] = v4; g_al[base + 5] = v5; g_al[base + 6] = v6; g_al[base + 7] = v7;
        }
    }
}

// ---------------- readout + all 7 timesteps + final linear: wave per graph ----------------
__global__ __launch_bounds__(256) void k_mol_all(const float* __restrict__ mb, const float* __restrict__ W2,
                                                 const float* __restrict__ b2, float* __restrict__ dout) {
    __shared__ uint32_t ldsWa[H * H];
    __shared__ uint32_t ldsWb[H * H];
    __shared__ uint32_t ldsWc[H * H];
    __shared__ float lbc[4][52][2];     // per-wave hm/oj broadcast
    int tid = threadIdx.x;
    for (int i = tid; i < H * H; i += 256) {
        const float* s = g_wg2 + (size_t)i * 8;
        ldsWa[i] = f2bf(s[0]) | (f2bf(s[1]) << 16);
        ldsWb[i] = f2bf(s[2]) | (f2bf(s[3]) << 16);
        ldsWc[i] = f2bf(s[4]) | (f2bf(s[5]) << 16);
    }
    __syncthreads();
    int w = tid >> 6;
    int lane = tid & 63;
    int lj = lane < H ? lane : H - 1;
    int b = __builtin_amdgcn_readfirstlane(blockIdx.x * 4 + w);
    int gs = g_gs[b], ge = g_gs[b + 1];
    float oa = 0.f, ob = 0.f;
    int i = gs;
    for (; i + 2 <= ge; i += 2) {
        oa += g_x2[(size_t)i * H + lane];
        ob += g_x2[(size_t)(i + 1) * H + lane];
    }
    if (i < ge) oa += g_x2[(size_t)i * H + lane];
    float oj = fmaxf(oa + ob, 0.f);
    float wvl = g_wv[lane];
    float mbl = mb[lj];
    const float4* bp = (const float4*)(g_bg2 + lane * 8);
    float4 b0 = bp[0];
    float4 b1v = bp[1];
#pragma unroll 1
    for (int t = 0; t < TSTEPS; ++t) {
        float arb = wave_sum((lane < H) ? oj * wvl : 0.f);
        float sa = 0.f, sb = 0.f, aa = 0.f, ab = 0.f;
        i = gs;
        for (; i + 2 <= ge; i += 2) {
            float ev0 = __expf(lrelu(g_al[i] + arb));
            float ev1 = __expf(lrelu(g_al[i + 1] + arb));
            sa += ev0; sb += ev1;
            aa = fmaf(ev0, g_xl[(size_t)i * H + lane], aa);
            ab = fmaf(ev1, g_xl[(size_t)(i + 1) * H + lane], ab);
        }
        if (i < ge) {
            float ev0 = __expf(lrelu(g_al[i] + arb));
            sa += ev0;
            aa = fmaf(ev0, g_xl[(size_t)i * H + lane], aa);
        }
        float inv = 1.f / (sa + sb + 1e-16f);
        float hm = elu1((aa + ab) * inv + mbl);
        if (lane < H) { lbc[w][lane][0] = hm; lbc[w][lane][1] = oj; }
        float gir = 0, giz = 0, gin = 0, ghr = 0, ghz = 0, ghn = 0;
#pragma unroll 2
        for (int k = 0; k < H; ++k) {
            uint32_t wa = ldsWa[k * H + lj];
            uint32_t wb = ldsWb[k * H + lj];
            uint32_t wc = ldsWc[k * H + lj];
            float2 ho = *(const float2*)&lbc[w][k][0];
            float hmk = ho.x, ok = ho.y;
            gir = fmaf(hmk, bflo(wa), gir); giz = fmaf(hmk, bfhi(wa), giz); gin = fmaf(hmk, bflo(wb), gin);
            ghr = fmaf(ok, bfhi(wb), ghr);  ghz = fmaf(ok, bflo(wc), ghz);  ghn = fmaf(ok, bfhi(wc), ghn);
        }
        float r = sigm(gir + b0.x + ghr + b0.w);
        float z = sigm(giz + b0.y + ghz + b1v.x);
        float nn2 = tanhf(gin + b0.z + r * (ghn + b1v.y));
        oj = fmaxf((1.f - z) * nn2 + z * oj, 0.f);
    }
    float fv = wave_sum((lane < H) ? oj * W2[lj] : 0.f);
    if (lane == 0) dout[b] = fv + b2[0];
}

extern "C" void kernel_launch(void* const* d_in, const int* in_sizes, int n_in,
                              void* d_out, int out_size, void* d_ws, size_t ws_size,
                              hipStream_t stream) {
    const float* x     = (const float*)d_in[0];
    const int*   ei    = (const int*)d_in[1];
    const float* ea    = (const float*)d_in[2];
    const int*   batch = (const int*)d_in[3];
    const float* W1    = (const float*)d_in[4];
    const float* b1    = (const float*)d_in[5];
    const float* We1   = (const float*)d_in[6];
    const float* attl  = (const float*)d_in[7];
    const float* attr_ = (const float*)d_in[8];
    const float* We2   = (const float*)d_in[9];
    const float* gb    = (const float*)d_in[10];
    const float* Wm    = (const float*)d_in[15];
    const float* asrc  = (const float*)d_in[16];
    const float* adst  = (const float*)d_in[17];
    const float* mb    = (const float*)d_in[18];
    const float* W2    = (const float*)d_in[23];
    const float* b2    = (const float*)d_in[24];
    float* dout = (float*)d_out;

    // CSR build + graph offsets
    k_init<<<SCAN_B, 256, 0, stream>>>(batch);
    k_count<<<NE / 256, 256, 0, stream>>>(ei);
    k_scan1<<<SCAN_B, 256, 0, stream>>>();
    k_scan2<<<1, 512, 0, stream>>>();
    k_scan3<<<SCAN_B, 256, 0, stream>>>();
    k_fill<<<NE / 256, 256, 0, stream>>>(ei, ea);

    // weight prep (both GRUs + wv fused)
    k_prep<<<(2 * H * H + 64 + 255) / 256, 256, 0, stream>>>(
        (const float*)d_in[11], (const float*)d_in[12], (const float*)d_in[13], (const float*)d_in[14],
        (const float*)d_in[19], (const float*)d_in[20], (const float*)d_in[21], (const float*)d_in[22],
        Wm, adst);

    // main pipeline
    k_lin1<<<(NN + 255) / 256, 256, 0, stream>>>(x, W1, b1, attr_, We1);
    k_gate<<<NN / 4, 256, 0, stream>>>(We1, attl);
    k_gategru<<<GG_BLOCKS, 256, 0, stream>>>(We2, gb, Wm, asrc);
    k_mol_all<<<NB / 4, 256, 0, stream>>>(mb, W2, b2, dout);
}